// Round 5
// baseline (865.515 us; speedup 1.0000x reference)
//
#include <hip/hip_runtime.h>

typedef unsigned long long u64;
typedef unsigned int u32;

#define KNN 19             // neighbors used (reference k=20 incl. self, minus self)
#define TOPK 20            // keep 20 incl. self
#define GRES 32            // grid cells per axis
#define NCELLS (GRES * GRES * GRES)
#define MAXBLK 512         // max candidate blocks (F/64); F=16384 -> 256
#define INIT_KEY ((((u64)0x7F800000u) << 32) | 0xFFFFFFFFu)   // (+inf, invalid id)

// ---------------------------------------------------------------------------
// Kernel 1: centroids + edges + Morton cell key + cell histogram.
// Centroid/edge math replicates reference op order exactly (contract off).
// Quantization only affects grouping quality, never correctness.
// ---------------------------------------------------------------------------
__device__ __forceinline__ u32 expand5(u32 x) {   // 5 bits -> every 3rd bit
  u32 m = 0;
  m |= (x & 1u);
  m |= (x & 2u) << 2;
  m |= (x & 4u) << 4;
  m |= (x & 8u) << 6;
  m |= (x & 16u) << 8;
  return m;
}

__global__ __launch_bounds__(256) void k_prep(
    const float* __restrict__ verts, const int* __restrict__ faces,
    float4* __restrict__ cent, float4* __restrict__ edges,
    u32* __restrict__ cellkey, u32* __restrict__ hist, int F) {
  #pragma clang fp contract(off)
  int f = blockIdx.x * 256 + threadIdx.x;
  if (f >= F) return;
  int i0 = faces[f * 3 + 0];
  int i1 = faces[f * 3 + 1];
  int i2 = faces[f * 3 + 2];
  float v0x = verts[i0 * 3 + 0], v0y = verts[i0 * 3 + 1], v0z = verts[i0 * 3 + 2];
  float v1x = verts[i1 * 3 + 0], v1y = verts[i1 * 3 + 1], v1z = verts[i1 * 3 + 2];
  float v2x = verts[i2 * 3 + 0], v2y = verts[i2 * 3 + 1], v2z = verts[i2 * 3 + 2];

  float cx = ((v0x + v1x) + v2x) / 3.0f;
  float cy = ((v0y + v1y) + v2y) / 3.0f;
  float cz = ((v0z + v1z) + v2z) / 3.0f;
  cent[f] = make_float4(cx, cy, cz, 0.0f);

  edges[f * 3 + 0] = make_float4(v1x - v0x, v1y - v0y, v1z - v0z, 0.0f);
  edges[f * 3 + 1] = make_float4(v2x - v1x, v2y - v1y, v2z - v1z, 0.0f);
  edges[f * 3 + 2] = make_float4(v0x - v2x, v0y - v2y, v0z - v2z, 0.0f);

  // Morton cell key (clamped quantization; binning quality only)
  int qx = (int)((cx + 6.0f) * (GRES / 12.0f));
  int qy = (int)((cy + 6.0f) * (GRES / 12.0f));
  int qz = (int)((cz + 6.0f) * (GRES / 12.0f));
  qx = qx < 0 ? 0 : (qx > GRES - 1 ? GRES - 1 : qx);
  qy = qy < 0 ? 0 : (qy > GRES - 1 ? GRES - 1 : qy);
  qz = qz < 0 ? 0 : (qz > GRES - 1 ? GRES - 1 : qz);
  u32 m = expand5((u32)qx) | (expand5((u32)qy) << 1) | (expand5((u32)qz) << 2);
  cellkey[f] = m;
  atomicAdd(&hist[m], 1u);
}

// ---------------------------------------------------------------------------
// Kernel 2: exclusive scan of the 32768-cell histogram -> cursor (one block).
// ---------------------------------------------------------------------------
__global__ __launch_bounds__(1024) void k_scan(
    const u32* __restrict__ hist, u32* __restrict__ cursor) {
  __shared__ u32 sums[1024];
  int t = threadIdx.x;
  int base = t * (NCELLS / 1024);
  u32 s = 0;
  for (int i = 0; i < NCELLS / 1024; ++i) s += hist[base + i];
  sums[t] = s;
  __syncthreads();
  for (int o = 1; o < 1024; o <<= 1) {
    u32 v = (t >= o) ? sums[t - o] : 0u;
    __syncthreads();
    sums[t] += v;
    __syncthreads();
  }
  u32 run = sums[t] - s;   // exclusive offset for this chunk
  for (int i = 0; i < NCELLS / 1024; ++i) {
    cursor[base + i] = run;
    run += hist[base + i];
  }
}

// ---------------------------------------------------------------------------
// Kernel 3: scatter faces into Morton-sorted order (counting sort pass 2).
// Intra-cell order is atomic-racy -> only internal layout varies; the final
// output depends only on exact key-ranked sets, so it stays deterministic.
// ---------------------------------------------------------------------------
__global__ __launch_bounds__(256) void k_scatter(
    const float4* __restrict__ cent, const u32* __restrict__ cellkey,
    u32* __restrict__ cursor, u32* __restrict__ ids,
    float4* __restrict__ centS, int F) {
  int f = blockIdx.x * 256 + threadIdx.x;
  if (f >= F) return;
  u32 pos = atomicAdd(&cursor[cellkey[f]], 1u);
  ids[pos] = (u32)f;
  centS[pos] = cent[f];
}

// ---------------------------------------------------------------------------
// Kernel 4: per-64-point-block bounding boxes (wave shuffle reduction).
// ---------------------------------------------------------------------------
__global__ __launch_bounds__(64) void k_bbox(
    const float4* __restrict__ centS, float4* __restrict__ blo,
    float4* __restrict__ bhi, int F) {
  int b = blockIdx.x;
  int t = threadIdx.x;
  int idx = b * 64 + t;
  bool ok = idx < F;
  float4 v = centS[ok ? idx : 0];
  float lx = ok ? v.x : __builtin_inff(), hx = ok ? v.x : -__builtin_inff();
  float ly = ok ? v.y : __builtin_inff(), hy = ok ? v.y : -__builtin_inff();
  float lz = ok ? v.z : __builtin_inff(), hz = ok ? v.z : -__builtin_inff();
  for (int m = 1; m < 64; m <<= 1) {
    lx = fminf(lx, __shfl_xor(lx, m));
    ly = fminf(ly, __shfl_xor(ly, m));
    lz = fminf(lz, __shfl_xor(lz, m));
    hx = fmaxf(hx, __shfl_xor(hx, m));
    hy = fmaxf(hy, __shfl_xor(hy, m));
    hz = fmaxf(hz, __shfl_xor(hz, m));
  }
  if (t == 0) {
    blo[b] = make_float4(lx, ly, lz, 0.0f);
    bhi[b] = make_float4(hx, hy, hz, 0.0f);
  }
}

// ---------------------------------------------------------------------------
// Kernel 5: exact pruned kNN. One wave per 64 Morton-sorted faces; thread per
// face keeps exact top-20 (incl. self) packed (d2bits<<32|orig_id) keys in
// registers. Candidate blocks scanned outward from own block; visited only if
// min-d2 to bbox (with conservative margin) can beat some lane's 20th-best.
// Real-candidate d2 is bit-exact contract-off; key order == lax.top_k order
// (stable lower-index tie-break). Exact regardless of binning quality.
// ---------------------------------------------------------------------------
__global__ __launch_bounds__(64) void k_knn(
    const float4* __restrict__ centS, const u32* __restrict__ ids,
    const float4* __restrict__ blo, const float4* __restrict__ bhi,
    int* __restrict__ nearest, int F, int nblk) {
  #pragma clang fp contract(off)
  __shared__ float4 s_lo[MAXBLK], s_hi[MAXBLK];
  __shared__ float4 s_c[64];
  __shared__ u32 s_i[64];

  int lane = threadIdx.x;
  int w = blockIdx.x;
  for (int i = lane; i < nblk; i += 64) { s_lo[i] = blo[i]; s_hi[i] = bhi[i]; }
  __syncthreads();

  int myPos = w * 64 + lane;
  bool live = myPos < F;
  float4 me = centS[live ? myPos : 0];

  u64 L[TOPK];
  #pragma unroll
  for (int p = 0; p < TOPK; ++p) L[p] = INIT_KEY;
  float l19 = __builtin_inff();

  for (int s = 0; s < 2 * nblk; ++s) {
    int b = (s & 1) ? (w - ((s + 1) >> 1)) : (w + (s >> 1));
    if ((unsigned)b >= (unsigned)nblk) continue;
    float4 lo = s_lo[b], hi = s_hi[b];
    float cx = fminf(fmaxf(me.x, lo.x), hi.x);
    float cy = fminf(fmaxf(me.y, lo.y), hi.y);
    float cz = fminf(fmaxf(me.z, lo.z), hi.z);
    float dx = me.x - cx, dy = me.y - cy, dz = me.z - cz;
    float dmin = ((dx * dx + dy * dy) + dz * dz) * 0.999999f;  // conservative
    bool need = live && (dmin <= l19);
    if (__any(need)) {
      int base = b * 64;
      {
        int cidx = base + lane;
        bool okc = cidx < F;
        float4 cv = centS[okc ? cidx : 0];
        u32 iv = okc ? ids[cidx] : 0xFFFFFFFFu;
        if (!okc) cv = make_float4(1e30f, 1e30f, 1e30f, 0.0f);
        s_c[lane] = cv;
        s_i[lane] = iv;
      }
      // single-wave block: LDS write->read ordered by lgkmcnt (compiler)
      #pragma unroll 4
      for (int q = 0; q < 64; ++q) {
        float4 cj = s_c[q];
        float ddx = me.x - cj.x, ddy = me.y - cj.y, ddz = me.z - cj.z;
        float d2 = (ddx * ddx + ddy * ddy) + ddz * ddz;   // bit-exact form
        u64 key = (((u64)__float_as_uint(d2)) << 32) | (u64)s_i[q];
        int js = base + q;
        key = (js == myPos) ? ~0ULL : key;                 // exclude self pos
        if (key < L[TOPK - 1]) {
          u64 prev = key;
          #pragma unroll
          for (int p = 0; p < TOPK; ++p) {
            u64 o = L[p];
            L[p] = prev < o ? prev : o;
            prev = key < o ? o : key;
          }
          l19 = __uint_as_float((u32)(L[TOPK - 1] >> 32));
        }
      }
    }
  }

  if (live) {
    u32 myId = ids[myPos];
    int outn = 0;
    #pragma unroll
    for (int p = 0; p < TOPK; ++p) {
      u32 idp = (u32)L[p];
      if (idp != myId && idp != 0xFFFFFFFFu && outn < KNN) {
        nearest[(size_t)myId * KNN + outn] = (int)idp;
        ++outn;
      }
    }
  }
}

// ---------------------------------------------------------------------------
// Kernel 6: one thread per (face, neighbor): 3x3 segment-pair crossing count.
// ---------------------------------------------------------------------------
__global__ __launch_bounds__(256) void k_cross(
    const float4* __restrict__ edges, const int* __restrict__ nearest,
    int* __restrict__ ccbuf, int total) {
  #pragma clang fp contract(off)
  int idx = blockIdx.x * 256 + threadIdx.x;
  if (idx >= total) return;
  int f = idx / KNN;
  int g = nearest[idx];

  float e[3][3], nb[3][3];
  #pragma unroll
  for (int a = 0; a < 3; ++a) {
    float4 t = edges[f * 3 + a];
    e[a][0] = t.x; e[a][1] = t.y; e[a][2] = t.z;
  }
  #pragma unroll
  for (int b = 0; b < 3; ++b) {
    float4 t = edges[g * 3 + b];
    nb[b][0] = t.x; nb[b][1] = t.y; nb[b][2] = t.z;
  }

  int cc = 0;
  #pragma unroll
  for (int a = 0; a < 3; ++a) {
    #pragma unroll
    for (int b = 0; b < 3; ++b) {
      float c0 = e[a][1] * nb[b][2] - e[a][2] * nb[b][1];
      float c1 = e[a][2] * nb[b][0] - e[a][0] * nb[b][2];
      float c2 = e[a][0] * nb[b][1] - e[a][1] * nb[b][0];
      float den = (c0 * e[a][0] + c1 * e[a][1]) + c2 * e[a][2];
      float tn  = (c0 * nb[b][0] + c1 * nb[b][1]) + c2 * nb[b][2];
      float un  = (c0 * e[b][0]  + c1 * e[b][1])  + c2 * e[b][2];
      float t = tn / den;
      float u = un / den;
      if (t >= 0.0f && t <= 1.0f && u >= 0.0f && u <= 1.0f) ++cc;
    }
  }
  ccbuf[idx] = cc;
}

// ---------------------------------------------------------------------------
// Kernel 7: per-face weighted sum, block-reduced.
// ---------------------------------------------------------------------------
__global__ __launch_bounds__(256) void k_wsum(
    const int* __restrict__ ccbuf, const float* __restrict__ probs,
    float* __restrict__ partial, int F) {
  int f = blockIdx.x * 256 + threadIdx.x;
  float w = 0.0f;
  if (f < F) {
    int c = 0;
    #pragma unroll
    for (int s = 0; s < KNN; ++s) c += ccbuf[(size_t)f * KNN + s];
    w = probs[f] * (float)c;
  }
  __shared__ float red[256];
  red[threadIdx.x] = w;
  __syncthreads();
  #pragma unroll
  for (int s = 128; s > 0; s >>= 1) {
    if (threadIdx.x < s) red[threadIdx.x] += red[threadIdx.x + s];
    __syncthreads();
  }
  if (threadIdx.x == 0) partial[blockIdx.x] = red[0];
}

// ---------------------------------------------------------------------------
// Kernel 8: deterministic final reduction; /F exact (F = 2^14)
// ---------------------------------------------------------------------------
__global__ void k_final(const float* __restrict__ partial, float* __restrict__ out,
                        int nblk, float invF) {
  if (threadIdx.x == 0 && blockIdx.x == 0) {
    float s = 0.0f;
    for (int i = 0; i < nblk; ++i) s += partial[i];
    out[0] = s * invF;
  }
}

extern "C" void kernel_launch(void* const* d_in, const int* in_sizes, int n_in,
                              void* d_out, int out_size, void* d_ws, size_t ws_size,
                              hipStream_t stream) {
  const float* verts = (const float*)d_in[0];
  const int*   faces = (const int*)d_in[1];
  const float* probs = (const float*)d_in[2];
  float* out = (float*)d_out;
  const int F = in_sizes[2];            // 16384
  const int total = F * KNN;
  const int nblk64 = (F + 63) / 64;     // 256 candidate blocks

  char* ws = (char*)d_ws;
  size_t off = 0;
  auto take = [&](size_t bytes) { char* p = ws + off; off += (bytes + 255) & ~(size_t)255; return p; };

  float4* cent    = (float4*)take((size_t)F * sizeof(float4));
  float4* edges   = (float4*)take((size_t)F * 3 * sizeof(float4));
  u32*    cellkey = (u32*)   take((size_t)F * sizeof(u32));
  u32*    hist    = (u32*)   take((size_t)NCELLS * sizeof(u32));
  u32*    cursor  = (u32*)   take((size_t)NCELLS * sizeof(u32));
  u32*    ids     = (u32*)   take((size_t)F * sizeof(u32));
  float4* centS   = (float4*)take((size_t)F * sizeof(float4));
  float4* blo     = (float4*)take((size_t)nblk64 * sizeof(float4));
  float4* bhi     = (float4*)take((size_t)nblk64 * sizeof(float4));
  int*    nearest = (int*)   take((size_t)total * sizeof(int));
  int*    ccbuf   = (int*)   take((size_t)total * sizeof(int));
  float*  partial = (float*) take(256 * sizeof(float));

  int nblk256 = (F + 255) / 256;        // 64

  hipMemsetAsync(hist, 0, (size_t)NCELLS * sizeof(u32), stream);
  k_prep   <<<nblk256, 256, 0, stream>>>(verts, faces, cent, edges, cellkey, hist, F);
  k_scan   <<<1, 1024, 0, stream>>>(hist, cursor);
  k_scatter<<<nblk256, 256, 0, stream>>>(cent, cellkey, cursor, ids, centS, F);
  k_bbox   <<<nblk64, 64, 0, stream>>>(centS, blo, bhi, F);
  k_knn    <<<nblk64, 64, 0, stream>>>(centS, ids, blo, bhi, nearest, F, nblk64);
  k_cross  <<<(total + 255) / 256, 256, 0, stream>>>(edges, nearest, ccbuf, total);
  k_wsum   <<<nblk256, 256, 0, stream>>>(ccbuf, probs, partial, F);
  k_final  <<<1, 64, 0, stream>>>(partial, out, nblk256, 1.0f / (float)F);
}

// Round 6
// 585.649 us; speedup vs baseline: 1.4779x; 1.4779x over previous
//
#include <hip/hip_runtime.h>

typedef unsigned long long u64;
typedef unsigned int u32;

#define KNN 19             // neighbors used (reference k=20 incl. self, minus self)
#define TOPK 20            // keep 20 incl. self
#define GRES 32            // grid cells per axis
#define NCELLS (GRES * GRES * GRES)
#define WPG 4              // scanner waves per 64-face group
#define INIT_KEY ((((u64)0x7F800000u) << 32) | 0xFFFFFFFFu)   // (+inf, invalid id)

// ---------------------------------------------------------------------------
// Kernel 1: centroids + edges + Morton cell key + cell histogram.
// Centroid/edge math replicates reference op order exactly (contract off).
// Quantization only affects grouping quality, never correctness.
// ---------------------------------------------------------------------------
__device__ __forceinline__ u32 expand5(u32 x) {   // 5 bits -> every 3rd bit
  u32 m = 0;
  m |= (x & 1u);
  m |= (x & 2u) << 2;
  m |= (x & 4u) << 4;
  m |= (x & 8u) << 6;
  m |= (x & 16u) << 8;
  return m;
}

__global__ __launch_bounds__(256) void k_prep(
    const float* __restrict__ verts, const int* __restrict__ faces,
    float4* __restrict__ cent, float4* __restrict__ edges,
    u32* __restrict__ cellkey, u32* __restrict__ hist, int F) {
  #pragma clang fp contract(off)
  int f = blockIdx.x * 256 + threadIdx.x;
  if (f >= F) return;
  int i0 = faces[f * 3 + 0];
  int i1 = faces[f * 3 + 1];
  int i2 = faces[f * 3 + 2];
  float v0x = verts[i0 * 3 + 0], v0y = verts[i0 * 3 + 1], v0z = verts[i0 * 3 + 2];
  float v1x = verts[i1 * 3 + 0], v1y = verts[i1 * 3 + 1], v1z = verts[i1 * 3 + 2];
  float v2x = verts[i2 * 3 + 0], v2y = verts[i2 * 3 + 1], v2z = verts[i2 * 3 + 2];

  float cx = ((v0x + v1x) + v2x) / 3.0f;
  float cy = ((v0y + v1y) + v2y) / 3.0f;
  float cz = ((v0z + v1z) + v2z) / 3.0f;
  cent[f] = make_float4(cx, cy, cz, 0.0f);

  edges[f * 3 + 0] = make_float4(v1x - v0x, v1y - v0y, v1z - v0z, 0.0f);
  edges[f * 3 + 1] = make_float4(v2x - v1x, v2y - v1y, v2z - v1z, 0.0f);
  edges[f * 3 + 2] = make_float4(v0x - v2x, v0y - v2y, v0z - v2z, 0.0f);

  int qx = (int)((cx + 6.0f) * (GRES / 12.0f));
  int qy = (int)((cy + 6.0f) * (GRES / 12.0f));
  int qz = (int)((cz + 6.0f) * (GRES / 12.0f));
  qx = qx < 0 ? 0 : (qx > GRES - 1 ? GRES - 1 : qx);
  qy = qy < 0 ? 0 : (qy > GRES - 1 ? GRES - 1 : qy);
  qz = qz < 0 ? 0 : (qz > GRES - 1 ? GRES - 1 : qz);
  u32 m = expand5((u32)qx) | (expand5((u32)qy) << 1) | (expand5((u32)qz) << 2);
  cellkey[f] = m;
  atomicAdd(&hist[m], 1u);
}

// ---------------------------------------------------------------------------
// Kernel 2: exclusive scan of the 32768-cell histogram -> cursor (one block).
// ---------------------------------------------------------------------------
__global__ __launch_bounds__(1024) void k_scan(
    const u32* __restrict__ hist, u32* __restrict__ cursor) {
  __shared__ u32 sums[1024];
  int t = threadIdx.x;
  int base = t * (NCELLS / 1024);
  u32 s = 0;
  for (int i = 0; i < NCELLS / 1024; ++i) s += hist[base + i];
  sums[t] = s;
  __syncthreads();
  for (int o = 1; o < 1024; o <<= 1) {
    u32 v = (t >= o) ? sums[t - o] : 0u;
    __syncthreads();
    sums[t] += v;
    __syncthreads();
  }
  u32 run = sums[t] - s;
  for (int i = 0; i < NCELLS / 1024; ++i) {
    cursor[base + i] = run;
    run += hist[base + i];
  }
}

// ---------------------------------------------------------------------------
// Kernel 3: scatter faces into Morton-sorted order. Intra-cell order is
// atomic-racy; output depends only on exact key-ranked sets -> deterministic.
// ---------------------------------------------------------------------------
__global__ __launch_bounds__(256) void k_scatter(
    const float4* __restrict__ cent, const u32* __restrict__ cellkey,
    u32* __restrict__ cursor, u32* __restrict__ ids,
    float4* __restrict__ centS, int F) {
  int f = blockIdx.x * 256 + threadIdx.x;
  if (f >= F) return;
  u32 pos = atomicAdd(&cursor[cellkey[f]], 1u);
  ids[pos] = (u32)f;
  centS[pos] = cent[f];
}

// ---------------------------------------------------------------------------
// Kernel 4: per-64-point-block bounding boxes (wave shuffle reduction).
// ---------------------------------------------------------------------------
__global__ __launch_bounds__(64) void k_bbox(
    const float4* __restrict__ centS, float4* __restrict__ blo,
    float4* __restrict__ bhi, int F) {
  int b = blockIdx.x;
  int t = threadIdx.x;
  int idx = b * 64 + t;
  bool ok = idx < F;
  float4 v = centS[ok ? idx : 0];
  float lx = ok ? v.x : __builtin_inff(), hx = ok ? v.x : -__builtin_inff();
  float ly = ok ? v.y : __builtin_inff(), hy = ok ? v.y : -__builtin_inff();
  float lz = ok ? v.z : __builtin_inff(), hz = ok ? v.z : -__builtin_inff();
  for (int m = 1; m < 64; m <<= 1) {
    lx = fminf(lx, __shfl_xor(lx, m));
    ly = fminf(ly, __shfl_xor(ly, m));
    lz = fminf(lz, __shfl_xor(lz, m));
    hx = fmaxf(hx, __shfl_xor(hx, m));
    hy = fmaxf(hy, __shfl_xor(hy, m));
    hz = fmaxf(hz, __shfl_xor(hz, m));
  }
  if (t == 0) {
    blo[b] = make_float4(lx, ly, lz, 0.0f);
    bhi[b] = make_float4(hx, hy, hz, 0.0f);
  }
}

// ---------------------------------------------------------------------------
// Kernel 5: exact pruned kNN, 4 scanner waves per 64-face group.
// Wave w of group g scans Morton-rings r = w+1, w+5, ... (both sides);
// wave 0 additionally scans the own block (sole owner -> no duplicate keys
// across waves). A ring block is visited only if min-d2(lane, bbox)*(1-1e-6)
// <= that lane's current 20th-best for some lane (wave vote). Candidate d2
// is bit-exact contract-off; packed (d2bits<<32|orig_id) keys reproduce
// lax.top_k's stable tie-break. Exact regardless of binning quality.
// Candidates are read straight from global with wave-uniform addresses
// (broadcast loads; the R2-R4 pattern that sustained ~98% VALUBusy).
// ---------------------------------------------------------------------------
__global__ __launch_bounds__(256) void k_knn(
    const float4* __restrict__ centS, const u32* __restrict__ ids,
    const float4* __restrict__ blo, const float4* __restrict__ bhi,
    int* __restrict__ nearest, int F, int nblk) {
  #pragma clang fp contract(off)
  __shared__ u64 s_lists[(WPG - 1) * 64 * TOPK];   // 30720 B

  int lane = threadIdx.x & 63;
  int w    = threadIdx.x >> 6;
  int g    = blockIdx.x;

  int myPos = g * 64 + lane;
  bool live = myPos < F;
  float4 me = centS[live ? myPos : 0];

  u64 L[TOPK];
  #pragma unroll
  for (int p = 0; p < TOPK; ++p) L[p] = INIT_KEY;
  float l19 = __builtin_inff();

  auto visit = [&](int b) {
    int base = b * 64;
    int cnt = (base + 64 <= F) ? 64 : (F - base);
    #pragma unroll 4
    for (int q = 0; q < cnt; ++q) {
      int jj = base + q;                      // wave-uniform
      float4 cj = centS[jj];
      u32 ij = ids[jj];
      float ddx = me.x - cj.x, ddy = me.y - cj.y, ddz = me.z - cj.z;
      float d2 = (ddx * ddx + ddy * ddy) + ddz * ddz;   // bit-exact form
      u64 key = (((u64)__float_as_uint(d2)) << 32) | (u64)ij;
      if (key < L[TOPK - 1]) {
        u64 prev = key;
        #pragma unroll
        for (int p = 0; p < TOPK; ++p) {
          u64 o = L[p];
          L[p] = prev < o ? prev : o;
          prev = key < o ? o : key;
        }
        l19 = __uint_as_float((u32)(L[TOPK - 1] >> 32));
      }
    }
  };

  auto check_visit = [&](int b) {
    float4 lo = blo[b], hi = bhi[b];
    float cx = fminf(fmaxf(me.x, lo.x), hi.x);
    float cy = fminf(fmaxf(me.y, lo.y), hi.y);
    float cz = fminf(fmaxf(me.z, lo.z), hi.z);
    float dx = me.x - cx, dy = me.y - cy, dz = me.z - cz;
    float dmin = ((dx * dx + dy * dy) + dz * dz) * 0.999999f;  // conservative
    if (__any(live && dmin <= l19)) visit(b);
  };

  if (w == 0) visit(g);   // own block: wave 0 only (avoids duplicate keys)

  for (int r = 1 + w; r < nblk; r += WPG) {
    int bl = g - r;
    if (bl >= 0) check_visit(bl);
    int br = g + r;
    if (br < nblk) check_visit(br);
  }

  // merge the 4 wave lists per face (disjoint candidate sets -> exact union)
  if (w > 0) {
    #pragma unroll
    for (int p = 0; p < TOPK; ++p)
      s_lists[(p * (WPG - 1) + (w - 1)) * 64 + lane] = L[p];
  }
  __syncthreads();

  if (w == 0) {
    for (int wm = 0; wm < WPG - 1; ++wm) {
      #pragma unroll
      for (int p = 0; p < TOPK; ++p) {
        u64 key = s_lists[(p * (WPG - 1) + wm) * 64 + lane];
        if (key < L[TOPK - 1]) {
          u64 prev = key;
          #pragma unroll
          for (int t = 0; t < TOPK; ++t) {
            u64 o = L[t];
            L[t] = prev < o ? prev : o;
            prev = key < o ? o : key;
          }
        }
      }
    }
    if (live) {
      u32 myId = ids[myPos];
      int outn = 0;
      #pragma unroll
      for (int p = 0; p < TOPK; ++p) {
        u32 idp = (u32)L[p];
        if (idp != myId && idp != 0xFFFFFFFFu && outn < KNN) {
          nearest[(size_t)myId * KNN + outn] = (int)idp;
          ++outn;
        }
      }
    }
  }
}

// ---------------------------------------------------------------------------
// Kernel 6: one thread per (face, neighbor): 3x3 segment-pair crossing count.
// ---------------------------------------------------------------------------
__global__ __launch_bounds__(256) void k_cross(
    const float4* __restrict__ edges, const int* __restrict__ nearest,
    int* __restrict__ ccbuf, int total) {
  #pragma clang fp contract(off)
  int idx = blockIdx.x * 256 + threadIdx.x;
  if (idx >= total) return;
  int f = idx / KNN;
  int g = nearest[idx];

  float e[3][3], nb[3][3];
  #pragma unroll
  for (int a = 0; a < 3; ++a) {
    float4 t = edges[f * 3 + a];
    e[a][0] = t.x; e[a][1] = t.y; e[a][2] = t.z;
  }
  #pragma unroll
  for (int b = 0; b < 3; ++b) {
    float4 t = edges[g * 3 + b];
    nb[b][0] = t.x; nb[b][1] = t.y; nb[b][2] = t.z;
  }

  int cc = 0;
  #pragma unroll
  for (int a = 0; a < 3; ++a) {
    #pragma unroll
    for (int b = 0; b < 3; ++b) {
      float c0 = e[a][1] * nb[b][2] - e[a][2] * nb[b][1];
      float c1 = e[a][2] * nb[b][0] - e[a][0] * nb[b][2];
      float c2 = e[a][0] * nb[b][1] - e[a][1] * nb[b][0];
      float den = (c0 * e[a][0] + c1 * e[a][1]) + c2 * e[a][2];
      float tn  = (c0 * nb[b][0] + c1 * nb[b][1]) + c2 * nb[b][2];
      float un  = (c0 * e[b][0]  + c1 * e[b][1])  + c2 * e[b][2];
      float t = tn / den;
      float u = un / den;
      if (t >= 0.0f && t <= 1.0f && u >= 0.0f && u <= 1.0f) ++cc;
    }
  }
  ccbuf[idx] = cc;
}

// ---------------------------------------------------------------------------
// Kernel 7: per-face weighted sum, block-reduced.
// ---------------------------------------------------------------------------
__global__ __launch_bounds__(256) void k_wsum(
    const int* __restrict__ ccbuf, const float* __restrict__ probs,
    float* __restrict__ partial, int F) {
  int f = blockIdx.x * 256 + threadIdx.x;
  float w = 0.0f;
  if (f < F) {
    int c = 0;
    #pragma unroll
    for (int s = 0; s < KNN; ++s) c += ccbuf[(size_t)f * KNN + s];
    w = probs[f] * (float)c;
  }
  __shared__ float red[256];
  red[threadIdx.x] = w;
  __syncthreads();
  #pragma unroll
  for (int s = 128; s > 0; s >>= 1) {
    if (threadIdx.x < s) red[threadIdx.x] += red[threadIdx.x + s];
    __syncthreads();
  }
  if (threadIdx.x == 0) partial[blockIdx.x] = red[0];
}

// ---------------------------------------------------------------------------
// Kernel 8: deterministic final reduction; /F exact (F = 2^14)
// ---------------------------------------------------------------------------
__global__ void k_final(const float* __restrict__ partial, float* __restrict__ out,
                        int nblk, float invF) {
  if (threadIdx.x == 0 && blockIdx.x == 0) {
    float s = 0.0f;
    for (int i = 0; i < nblk; ++i) s += partial[i];
    out[0] = s * invF;
  }
}

extern "C" void kernel_launch(void* const* d_in, const int* in_sizes, int n_in,
                              void* d_out, int out_size, void* d_ws, size_t ws_size,
                              hipStream_t stream) {
  const float* verts = (const float*)d_in[0];
  const int*   faces = (const int*)d_in[1];
  const float* probs = (const float*)d_in[2];
  float* out = (float*)d_out;
  const int F = in_sizes[2];            // 16384
  const int total = F * KNN;
  const int nblk64 = (F + 63) / 64;     // 256 candidate blocks

  char* ws = (char*)d_ws;
  size_t off = 0;
  auto take = [&](size_t bytes) { char* p = ws + off; off += (bytes + 255) & ~(size_t)255; return p; };

  float4* cent    = (float4*)take((size_t)F * sizeof(float4));
  float4* edges   = (float4*)take((size_t)F * 3 * sizeof(float4));
  u32*    cellkey = (u32*)   take((size_t)F * sizeof(u32));
  u32*    hist    = (u32*)   take((size_t)NCELLS * sizeof(u32));
  u32*    cursor  = (u32*)   take((size_t)NCELLS * sizeof(u32));
  u32*    ids     = (u32*)   take((size_t)F * sizeof(u32));
  float4* centS   = (float4*)take((size_t)F * sizeof(float4));
  float4* blo     = (float4*)take((size_t)nblk64 * sizeof(float4));
  float4* bhi     = (float4*)take((size_t)nblk64 * sizeof(float4));
  int*    nearest = (int*)   take((size_t)total * sizeof(int));
  int*    ccbuf   = (int*)   take((size_t)total * sizeof(int));
  float*  partial = (float*) take(256 * sizeof(float));

  int nblk256 = (F + 255) / 256;        // 64

  hipMemsetAsync(hist, 0, (size_t)NCELLS * sizeof(u32), stream);
  k_prep   <<<nblk256, 256, 0, stream>>>(verts, faces, cent, edges, cellkey, hist, F);
  k_scan   <<<1, 1024, 0, stream>>>(hist, cursor);
  k_scatter<<<nblk256, 256, 0, stream>>>(cent, cellkey, cursor, ids, centS, F);
  k_bbox   <<<nblk64, 64, 0, stream>>>(centS, blo, bhi, F);
  k_knn    <<<nblk64, WPG * 64, 0, stream>>>(centS, ids, blo, bhi, nearest, F, nblk64);
  k_cross  <<<(total + 255) / 256, 256, 0, stream>>>(edges, nearest, ccbuf, total);
  k_wsum   <<<nblk256, 256, 0, stream>>>(ccbuf, probs, partial, F);
  k_final  <<<1, 64, 0, stream>>>(partial, out, nblk256, 1.0f / (float)F);
}